// Round 13
// baseline (302.151 us; speedup 1.0000x reference)
//
#include <hip/hip_runtime.h>
#include <hip/hip_bf16.h>

// SparseLinear as dense bf16 MFMA GEMM: out[b,o] = sum_i x[b,i]*W[o,i]
// C = A * B^T, M=8192, N=4096, K=4096. bias is dead in the reference.
// R13 = R10 (best: 233us GEMM, 16x16x32, 0 conflicts) + in-order counted
// LGKM read-ahead, reads kept PRE-barrier (R11's failure was post-barrier
// placement): tile-top issues A0+B0+B1 (16 reads), ph2 issues A1 (8, into
// separate aR2 set). LGKM(4)@ph1 / LGKM(8)@ph2 / LGKM(0)@ph3 retire
// exactly each phase's operands (DS retires in order), so B1's and A1's
// LDS service hides under q00/q01's MFMA clusters. Stage ledger identical
// to R10 (re-verified). 5 barriers/tile, vmcnt(4) gate per tile.
// T1 XCD swizzle; T2 XOR swizzle byte^=((row&7)<<4).

typedef short bf16x8 __attribute__((ext_vector_type(8)));
typedef float f32x4 __attribute__((ext_vector_type(4)));
typedef unsigned short u16x8 __attribute__((ext_vector_type(8)));

static constexpr int M_DIM = 8192;
static constexpr int N_DIM = 4096;
static constexpr int K_DIM = 4096;
static constexpr int BM = 256, BN = 256, BK = 64;
static constexpr int KT = K_DIM / BK;  // 64 K-tiles, 32 iters x 2 tiles

__device__ __forceinline__ unsigned short f2bf(float f) {
  unsigned int u = __builtin_bit_cast(unsigned int, f);
  u += 0x7fffu + ((u >> 16) & 1u);
  return (unsigned short)(u >> 16);
}

__global__ void cvt_f32_bf16(const float* __restrict__ in,
                             unsigned short* __restrict__ out, long n8) {
  long i = (long)blockIdx.x * blockDim.x + threadIdx.x;
  const long stride = (long)gridDim.x * blockDim.x;
  for (; i < n8; i += stride) {
    f32x4 a = ((const f32x4*)in)[2 * i];
    f32x4 b = ((const f32x4*)in)[2 * i + 1];
    u16x8 v;
    v[0] = f2bf(a[0]); v[1] = f2bf(a[1]); v[2] = f2bf(a[2]); v[3] = f2bf(a[3]);
    v[4] = f2bf(b[0]); v[5] = f2bf(b[1]); v[6] = f2bf(b[2]); v[7] = f2bf(b[3]);
    ((u16x8*)out)[i] = v;
  }
}

#define LGKM(N) asm volatile("s_waitcnt lgkmcnt(" #N ")" ::: "memory")
#define VMC(N) asm volatile("s_waitcnt vmcnt(" #N ")" ::: "memory")
#define SB0() __builtin_amdgcn_sched_barrier(0)
#define BAR()                        \
  do {                               \
    asm volatile("" ::: "memory");   \
    __builtin_amdgcn_s_barrier();    \
    asm volatile("" ::: "memory");   \
  } while (0)

__device__ __forceinline__ void gload16(const unsigned short* src,
                                        unsigned short* dst) {
  __builtin_amdgcn_global_load_lds(
      (const __attribute__((address_space(1))) void*)src,
      (__attribute__((address_space(3))) void*)dst, 16, 0, 0);
}

// Per-buffer layout (bytes): A rows 0-255 @0 (32 KB), B rows 0-255 @32768.
// Row stride 128 B. Swizzle: byte ^= ((row&7)<<4). k-half XOR precomputed
// (loop-invariant); mh/nh/fr offsets (>=2^11) add without carry into bit 6.

__global__ __launch_bounds__(512, 2) void gemmR13(
    const unsigned short* __restrict__ Ab, const unsigned short* __restrict__ Bb,
    float* __restrict__ C) {
  __shared__ unsigned short lds[2][32768];  // 2 x 64 KB

  const int tid = threadIdx.x;
  const int lane = tid & 63;
  const int wid = tid >> 6;   // 8 waves: 2M x 4N, wave-tile 128 x 64
  const int wr = wid >> 2;    // 0..1
  const int wc = wid & 3;     // 0..3
  const int l15 = lane & 15;

  // T1: XCD-aware bijective swizzle (512 blocks, %8==0)
  const int b0i = blockIdx.x;
  const int swz = (b0i & 7) * ((int)gridDim.x >> 3) + (b0i >> 3);
  const int row0 = (swz / (N_DIM / BN)) * BM;
  const int col0 = (swz % (N_DIM / BN)) * BN;

  // swizzled read bases (bytes, buffer-relative); k-half XOR precomputed
  const int kg = (((lane >> 4) << 4) ^ ((lane & 7) << 4));
  const int abase = wr * 16384 + l15 * 128 + kg;
  const int abase2 = abase ^ 64;
  const int bbase = 32768 + (wc >> 1) * 16384 + (wc & 1) * 8192 + l15 * 128 + kg;
  const int bbase2 = bbase ^ 64;

  // staging: inverse-swizzled global sources [half][inst]
  const unsigned short* pA[2][2];
  const unsigned short* pB[2][2];
#pragma unroll
  for (int r = 0; r < 2; ++r) {
    int q = r * 8192 + tid * 16;
    int lo = q ^ (((q >> 7) & 7) << 4);
    int grow = lo >> 7;            // 0..127
    int gk = (lo & 127) >> 1;      // 0..63
#pragma unroll
    for (int h = 0; h < 2; ++h) {
      pA[h][r] = Ab + (size_t)(row0 + h * 128 + grow) * K_DIM + gk;
      pB[h][r] = Bb + (size_t)(col0 + h * 128 + grow) * K_DIM + gk;
    }
  }

#define STG_A(BUF, H, KEL)                                                 \
  do {                                                                     \
    gload16(pA[H][0] + (KEL), &lds[BUF][0] + (H) * 8192 + wid * 512);      \
    gload16(pA[H][1] + (KEL), &lds[BUF][0] + (H) * 8192 + 4096 + wid * 512); \
  } while (0)
#define STG_B(BUF, H, KEL)                                                 \
  do {                                                                     \
    gload16(pB[H][0] + (KEL), &lds[BUF][0] + 16384 + (H) * 8192 + wid * 512); \
    gload16(pB[H][1] + (KEL), &lds[BUF][0] + 16384 + (H) * 8192 + 4096 + wid * 512); \
  } while (0)

  f32x4 acc[8][4] = {};
  bf16x8 aR[8], aR2[8], bR0[4], bR1[4];  // A0 / A1 / B0 / B1 operand sets

#define READ_A(BUF, MH, AR)                                                \
  _Pragma("unroll") for (int fr = 0; fr < 4; ++fr) {                       \
    AR[fr * 2 + 0] = *(const bf16x8*)((BUF) + abase + (MH) * 8192 + fr * 2048);  \
    AR[fr * 2 + 1] = *(const bf16x8*)((BUF) + abase2 + (MH) * 8192 + fr * 2048); \
  }
#define READ_B(BUF, NH, BR)                                                \
  _Pragma("unroll") for (int nf = 0; nf < 2; ++nf) {                       \
    BR[nf * 2 + 0] = *(const bf16x8*)((BUF) + bbase + (NH) * 4096 + nf * 2048);  \
    BR[nf * 2 + 1] = *(const bf16x8*)((BUF) + bbase2 + (NH) * 4096 + nf * 2048); \
  }
#define MFMA_Q(MH, NH, AR, BR)                                             \
  _Pragma("unroll") for (int fr = 0; fr < 4; ++fr)                         \
    _Pragma("unroll") for (int nf = 0; nf < 2; ++nf) {                     \
      acc[(MH) * 4 + fr][(NH) * 2 + nf] =                                  \
          __builtin_amdgcn_mfma_f32_16x16x32_bf16(                         \
              AR[fr * 2 + 0], BR[nf * 2 + 0],                              \
              acc[(MH) * 4 + fr][(NH) * 2 + nf], 0, 0, 0);                 \
      acc[(MH) * 4 + fr][(NH) * 2 + nf] =                                  \
          __builtin_amdgcn_mfma_f32_16x16x32_bf16(                         \
              AR[fr * 2 + 1], BR[nf * 2 + 1],                              \
              acc[(MH) * 4 + fr][(NH) * 2 + nf], 0, 0, 0);                 \
    }
#define PRIO1() __builtin_amdgcn_s_setprio(1)
#define PRIO0() __builtin_amdgcn_s_setprio(0)

  // prologue: tile0 (4 halves -> buf0) + tile1's B halves -> buf1.
  STG_A(0, 0, 0); STG_A(0, 1, 0); STG_B(0, 0, 0); STG_B(0, 1, 0);
  STG_B(1, 0, 64); STG_B(1, 1, 64);
  VMC(4);
  BAR();

  const char* b0 = (const char*)&lds[0][0];
  const char* b1 = (const char*)&lds[1][0];

#pragma unroll 1
  for (int i = 0; i < KT / 2; ++i) {
    const int t = 2 * i;
    const int kb = t * 64;
    const bool s2 = (t + 2 < KT), s3 = (t + 3 < KT);

    // ======== tile t (even, read buf0) ========
    // ph1: reads A0(8)+B0(4)+B1(4, ahead). stage Ah0(t+1)->buf1.
    //      LGKM(4): A0,B0 retired; B1 serviced under q00's MFMA.
    READ_A(b0, 0, aR)
    READ_B(b0, 0, bR0)
    READ_B(b0, 1, bR1)
    STG_A(1, 0, kb + 64);
    BAR(); LGKM(4); SB0(); PRIO1();
    MFMA_Q(0, 0, aR, bR0)
    PRIO0();

    // ph2: reads A1(8, ahead, own set). stage Ah1(t+1)->buf1.
    //      LGKM(8): B1 retired; A1 serviced under q01's MFMA.
    READ_A(b0, 1, aR2)
    STG_A(1, 1, kb + 64);
    BAR(); LGKM(8); SB0(); PRIO1();
    MFMA_Q(0, 1, aR, bR1)
    PRIO0();

    // ph3: no reads. stage Bh0(t+2)->buf0 (B0 reads retired at ph1-LGKM,
    //      every wave past ph2-BAR). LGKM(0): A1 retired.
    if (s2) STG_B(0, 0, kb + 128);
    BAR(); LGKM(0); SB0(); PRIO1();
    MFMA_Q(1, 1, aR2, bR1)
    PRIO0();

    // ph4: no reads, no LGKM (all operands in regs). stage Bh1(t+2)->buf0.
    if (s2) STG_B(0, 1, kb + 128);
    BAR(); SB0(); PRIO1();
    MFMA_Q(1, 0, aR2, bR0)
    PRIO0();
    if (s2) { VMC(4); } else { VMC(0); }  // t+1's 8 loads landed
    BAR();

    // ======== tile t+1 (odd, read buf1) ========
    // ph5: reads A0+B0+B1 from buf1. stage Ah0(t+2)->buf0.
    READ_A(b1, 0, aR)
    READ_B(b1, 0, bR0)
    READ_B(b1, 1, bR1)
    if (s2) STG_A(0, 0, kb + 128);
    BAR(); LGKM(4); SB0(); PRIO1();
    MFMA_Q(0, 0, aR, bR0)
    PRIO0();

    // ph6: reads A1. stage Ah1(t+2)->buf0.
    READ_A(b1, 1, aR2)
    if (s2) STG_A(0, 1, kb + 128);
    BAR(); LGKM(8); SB0(); PRIO1();
    MFMA_Q(0, 1, aR, bR1)
    PRIO0();

    // ph7: stage Bh0(t+3)->buf1.
    if (s3) STG_B(1, 0, kb + 192);
    BAR(); LGKM(0); SB0(); PRIO1();
    MFMA_Q(1, 1, aR2, bR1)
    PRIO0();

    // ph8: stage Bh1(t+3)->buf1.
    if (s3) STG_B(1, 1, kb + 192);
    BAR(); SB0(); PRIO1();
    MFMA_Q(1, 0, aR2, bR0)
    PRIO0();
    if (s3) { VMC(4); } else { VMC(0); }
    BAR();
  }

  // epilogue: 16x16 C/D layout (m89-verified): col=lane&15, row=(lane>>4)*4+j
#pragma unroll
  for (int mf = 0; mf < 8; ++mf) {
#pragma unroll
    for (int nf = 0; nf < 4; ++nf) {
      const int gr = row0 + wr * 128 + mf * 16 + (lane >> 4) * 4;
      const int gc = col0 + wc * 64 + nf * 16 + l15;
      float* cp = C + (size_t)gr * N_DIM + gc;
#pragma unroll
      for (int j = 0; j < 4; ++j) cp[(size_t)j * N_DIM] = acc[mf][nf][j];
    }
  }
}

// ---- fallback (ws too small): reg-staged f32->bf16 kernel ------------------
__global__ __launch_bounds__(256) void gemm_fb(const float* __restrict__ Af,
                                               const float* __restrict__ Bf,
                                               float* __restrict__ C) {
  __shared__ unsigned short sA[128 * 64];
  __shared__ unsigned short sB[128 * 64];
  const int tid = threadIdx.x;
  const int lane = tid & 63;
  const int wid = tid >> 6;
  const int wr = wid >> 1, wc = wid & 1;
  const int cpx = (int)gridDim.x >> 3;
  const int swzb = ((int)blockIdx.x & 7) * cpx + ((int)blockIdx.x >> 3);
  const int row0 = (swzb / (N_DIM / 128)) * 128;
  const int col0 = (swzb % (N_DIM / 128)) * 128;
  f32x4 acc[4][4] = {};
  const int fbase = tid * 8;
  for (int kt = 0; kt < K_DIM; kt += 64) {
#pragma unroll
    for (int p = 0; p < 4; ++p) {
      const int f = fbase + p * 2048;
      const int r = f >> 6, kc = f & 63;
      const float* gA = Af + (size_t)(row0 + r) * K_DIM + kt + kc;
      const float* gB = Bf + (size_t)(col0 + r) * K_DIM + kt + kc;
      f32x4 a0 = ((const f32x4*)gA)[0], a1 = ((const f32x4*)gA)[1];
      f32x4 c0 = ((const f32x4*)gB)[0], c1 = ((const f32x4*)gB)[1];
      u16x8 va, vb;
      va[0] = f2bf(a0[0]); va[1] = f2bf(a0[1]); va[2] = f2bf(a0[2]); va[3] = f2bf(a0[3]);
      va[4] = f2bf(a1[0]); va[5] = f2bf(a1[1]); va[6] = f2bf(a1[2]); va[7] = f2bf(a1[3]);
      vb[0] = f2bf(c0[0]); vb[1] = f2bf(c0[1]); vb[2] = f2bf(c0[2]); vb[3] = f2bf(c0[3]);
      vb[4] = f2bf(c1[0]); vb[5] = f2bf(c1[1]); vb[6] = f2bf(c1[2]); vb[7] = f2bf(c1[3]);
      *(u16x8*)&sA[f] = va;
      *(u16x8*)&sB[f] = vb;
    }
    __syncthreads();
#pragma unroll
    for (int kk = 0; kk < 2; ++kk) {
      bf16x8 a[4], b[4];
#pragma unroll
      for (int m = 0; m < 4; ++m)
        a[m] = *(const bf16x8*)&sA[(wr * 64 + m * 16 + (lane & 15)) * 64 + kk * 32 + (lane >> 4) * 8];
#pragma unroll
      for (int n = 0; n < 4; ++n)
        b[n] = *(const bf16x8*)&sB[(wc * 64 + n * 16 + (lane & 15)) * 64 + kk * 32 + (lane >> 4) * 8];
#pragma unroll
      for (int m = 0; m < 4; ++m)
#pragma unroll
        for (int n = 0; n < 4; ++n)
          acc[m][n] = __builtin_amdgcn_mfma_f32_16x16x32_bf16(a[m], b[n], acc[m][n], 0, 0, 0);
    }
    __syncthreads();
  }
#pragma unroll
  for (int m = 0; m < 4; ++m)
#pragma unroll
    for (int n = 0; n < 4; ++n) {
      const int gr = row0 + wr * 64 + m * 16 + (lane >> 4) * 4;
      const int gc = col0 + wc * 64 + n * 16 + (lane & 15);
      float* cp = C + (size_t)gr * N_DIM + gc;
#pragma unroll
      for (int j = 0; j < 4; ++j) cp[(size_t)j * N_DIM] = acc[m][n][j];
    }
}

extern "C" void kernel_launch(void* const* d_in, const int* in_sizes, int n_in,
                              void* d_out, int out_size, void* d_ws, size_t ws_size,
                              hipStream_t stream) {
  const float* x = (const float*)d_in[0];  // [8192, 4096]
  const float* W = (const float*)d_in[1];  // [4096, 4096]
  float* out = (float*)d_out;              // [8192, 4096] f32

  const size_t xb_bytes = (size_t)M_DIM * K_DIM * 2;  // 64 MiB
  const size_t wb_bytes = (size_t)N_DIM * K_DIM * 2;  // 32 MiB

  if (ws_size >= xb_bytes + wb_bytes) {
    unsigned short* Xb = (unsigned short*)d_ws;
    unsigned short* Wb = (unsigned short*)((char*)d_ws + xb_bytes);
    cvt_f32_bf16<<<2048, 256, 0, stream>>>(x, Xb, (long)M_DIM * K_DIM / 8);
    cvt_f32_bf16<<<2048, 256, 0, stream>>>(W, Wb, (long)N_DIM * K_DIM / 8);
    const dim3 grid((M_DIM / BM) * (N_DIM / BN));  // 32*16 = 512 blocks
    gemmR13<<<grid, dim3(512), 0, stream>>>(Xb, Wb, out);
  } else {
    gemm_fb<<<dim3(2048), dim3(256), 0, stream>>>(x, W, out);
  }
}

// Round 14
// 254.168 us; speedup vs baseline: 1.1888x; 1.1888x over previous
//
#include <hip/hip_runtime.h>
#include <hip/hip_bf16.h>

// SparseLinear as dense bf16 MFMA GEMM: out[b,o] = sum_i x[b,i]*W[o,i]
// C = A * B^T, M=8192, N=4096, K=4096. bias is dead in the reference.
// R14 = R10 exact revert (best measured: GEMM 233us, MfmaUtil 52.6%,
// 0 bank conflicts) + fused single-launch f32->bf16 convert.
// R10 structure: 256x256 tile, BK=64, 8 waves (2Mx4N), 16x16x32 MFMA,
// LDS 128 KiB = buf[2] x {A[256][64k], B[256][64k]}, quadrant phases
// {12,4,8,0} ds_read_b128 issued PRE-barrier / consumed POST-barrier via
// single MID barrier per phase (waves de-phase by <=1 phase -> LDS service
// overlaps MFMA cross-wave), 1 half-tile staged per phase, vmcnt(4) gate
// once per K-tile. T1 XCD swizzle; T2 XOR swizzle byte^=((row&7)<<4);
// loop-invariant k-half XOR bases precomputed.
// Post-mortem ledger (R11/R13): counted-LGKM read-ahead regresses in this
// structure both post- and pre-barrier; 32x32x16 regresses (fixed 2.5e7
// conflict floor of the l31 pattern). R10 is the plateau of this family.

typedef short bf16x8 __attribute__((ext_vector_type(8)));
typedef float f32x4 __attribute__((ext_vector_type(4)));
typedef unsigned short u16x8 __attribute__((ext_vector_type(8)));

static constexpr int M_DIM = 8192;
static constexpr int N_DIM = 4096;
static constexpr int K_DIM = 4096;
static constexpr int BM = 256, BN = 256, BK = 64;
static constexpr int KT = K_DIM / BK;  // 64 K-tiles, 32 iters x 2 tiles

__device__ __forceinline__ unsigned short f2bf(float f) {
  unsigned int u = __builtin_bit_cast(unsigned int, f);
  u += 0x7fffu + ((u >> 16) & 1u);
  return (unsigned short)(u >> 16);
}

// fused convert: grid-stride over x (nx8 vec8 chunks) then W (nw8 chunks)
__global__ void cvt_fused(const float* __restrict__ x,
                          unsigned short* __restrict__ xo, long nx8,
                          const float* __restrict__ w,
                          unsigned short* __restrict__ wo, long nw8) {
  const long stride = (long)gridDim.x * blockDim.x;
  long i = (long)blockIdx.x * blockDim.x + threadIdx.x;
  for (; i < nx8 + nw8; i += stride) {
    const float* in = (i < nx8) ? x : w;
    unsigned short* out = (i < nx8) ? xo : wo;
    const long j = (i < nx8) ? i : i - nx8;
    f32x4 a = ((const f32x4*)in)[2 * j];
    f32x4 b = ((const f32x4*)in)[2 * j + 1];
    u16x8 v;
    v[0] = f2bf(a[0]); v[1] = f2bf(a[1]); v[2] = f2bf(a[2]); v[3] = f2bf(a[3]);
    v[4] = f2bf(b[0]); v[5] = f2bf(b[1]); v[6] = f2bf(b[2]); v[7] = f2bf(b[3]);
    ((u16x8*)out)[j] = v;
  }
}

#define LGKM(N) asm volatile("s_waitcnt lgkmcnt(" #N ")" ::: "memory")
#define VMC(N) asm volatile("s_waitcnt vmcnt(" #N ")" ::: "memory")
#define SB0() __builtin_amdgcn_sched_barrier(0)
#define BAR()                        \
  do {                               \
    asm volatile("" ::: "memory");   \
    __builtin_amdgcn_s_barrier();    \
    asm volatile("" ::: "memory");   \
  } while (0)

__device__ __forceinline__ void gload16(const unsigned short* src,
                                        unsigned short* dst) {
  __builtin_amdgcn_global_load_lds(
      (const __attribute__((address_space(1))) void*)src,
      (__attribute__((address_space(3))) void*)dst, 16, 0, 0);
}

// Per-buffer layout (bytes): A rows 0-255 @0 (32 KB), B rows 0-255 @32768.
// Row stride 128 B. Swizzle: byte ^= ((row&7)<<4); row&7 == lane&7 for all
// fragment reads. k-half offset (64 = bit 6) XOR-composes; loop-invariant,
// so both bases precomputed. mh/nh/fr offsets (>=2^11) add without carry.

__global__ __launch_bounds__(512, 2) void gemmR10(
    const unsigned short* __restrict__ Ab, const unsigned short* __restrict__ Bb,
    float* __restrict__ C) {
  __shared__ unsigned short lds[2][32768];  // 2 x 64 KB

  const int tid = threadIdx.x;
  const int lane = tid & 63;
  const int wid = tid >> 6;   // 8 waves: 2M x 4N, wave-tile 128 x 64
  const int wr = wid >> 2;    // 0..1
  const int wc = wid & 3;     // 0..3
  const int l15 = lane & 15;

  // T1: XCD-aware bijective swizzle (512 blocks, %8==0)
  const int b0i = blockIdx.x;
  const int swz = (b0i & 7) * ((int)gridDim.x >> 3) + (b0i >> 3);
  const int row0 = (swz / (N_DIM / BN)) * BM;
  const int col0 = (swz % (N_DIM / BN)) * BN;

  // swizzled read bases (bytes, buffer-relative); k-half XOR precomputed
  const int kg = (((lane >> 4) << 4) ^ ((lane & 7) << 4));
  const int abase = wr * 16384 + l15 * 128 + kg;
  const int abase2 = abase ^ 64;
  const int bbase = 32768 + (wc >> 1) * 16384 + (wc & 1) * 8192 + l15 * 128 + kg;
  const int bbase2 = bbase ^ 64;

  // staging: inverse-swizzled global sources [half][inst]
  const unsigned short* pA[2][2];
  const unsigned short* pB[2][2];
#pragma unroll
  for (int r = 0; r < 2; ++r) {
    int q = r * 8192 + tid * 16;
    int lo = q ^ (((q >> 7) & 7) << 4);
    int grow = lo >> 7;            // 0..127
    int gk = (lo & 127) >> 1;      // 0..63
#pragma unroll
    for (int h = 0; h < 2; ++h) {
      pA[h][r] = Ab + (size_t)(row0 + h * 128 + grow) * K_DIM + gk;
      pB[h][r] = Bb + (size_t)(col0 + h * 128 + grow) * K_DIM + gk;
    }
  }

#define STG_A(BUF, H, KEL)                                                 \
  do {                                                                     \
    gload16(pA[H][0] + (KEL), &lds[BUF][0] + (H) * 8192 + wid * 512);      \
    gload16(pA[H][1] + (KEL), &lds[BUF][0] + (H) * 8192 + 4096 + wid * 512); \
  } while (0)
#define STG_B(BUF, H, KEL)                                                 \
  do {                                                                     \
    gload16(pB[H][0] + (KEL), &lds[BUF][0] + 16384 + (H) * 8192 + wid * 512); \
    gload16(pB[H][1] + (KEL), &lds[BUF][0] + 16384 + (H) * 8192 + 4096 + wid * 512); \
  } while (0)

  f32x4 acc[8][4] = {};
  bf16x8 aR[8], bR0[4], bR1[4];

#define READ_A(BUF, MH)                                                    \
  _Pragma("unroll") for (int fr = 0; fr < 4; ++fr) {                       \
    aR[fr * 2 + 0] = *(const bf16x8*)((BUF) + abase + (MH) * 8192 + fr * 2048);  \
    aR[fr * 2 + 1] = *(const bf16x8*)((BUF) + abase2 + (MH) * 8192 + fr * 2048); \
  }
#define READ_B(BUF, NH, BR)                                                \
  _Pragma("unroll") for (int nf = 0; nf < 2; ++nf) {                       \
    BR[nf * 2 + 0] = *(const bf16x8*)((BUF) + bbase + (NH) * 4096 + nf * 2048);  \
    BR[nf * 2 + 1] = *(const bf16x8*)((BUF) + bbase2 + (NH) * 4096 + nf * 2048); \
  }
#define MFMA_Q(MH, NH, BR)                                                 \
  _Pragma("unroll") for (int fr = 0; fr < 4; ++fr)                         \
    _Pragma("unroll") for (int nf = 0; nf < 2; ++nf) {                     \
      acc[(MH) * 4 + fr][(NH) * 2 + nf] =                                  \
          __builtin_amdgcn_mfma_f32_16x16x32_bf16(                         \
              aR[fr * 2 + 0], BR[nf * 2 + 0],                              \
              acc[(MH) * 4 + fr][(NH) * 2 + nf], 0, 0, 0);                 \
      acc[(MH) * 4 + fr][(NH) * 2 + nf] =                                  \
          __builtin_amdgcn_mfma_f32_16x16x32_bf16(                         \
              aR[fr * 2 + 1], BR[nf * 2 + 1],                              \
              acc[(MH) * 4 + fr][(NH) * 2 + nf], 0, 0, 0);                 \
    }
// Single load-bearing barrier per phase (MID). Stage deadlines are
// guaranteed by the MID barrier chain (R10 ledger).
#define PH_MID()  BAR(); LGKM(0); SB0(); __builtin_amdgcn_s_setprio(1)
#define PH_CUT()  __builtin_amdgcn_s_setprio(0)

  // prologue: tile0 (4 halves -> buf0) + tile1's B halves -> buf1.
  STG_A(0, 0, 0); STG_A(0, 1, 0); STG_B(0, 0, 0); STG_B(0, 1, 0);
  STG_B(1, 0, 64); STG_B(1, 1, 64);
  VMC(4);
  BAR();

  const char* b0 = (const char*)&lds[0][0];
  const char* b1 = (const char*)&lds[1][0];

#pragma unroll 1
  for (int i = 0; i < KT / 2; ++i) {
    const int t = 2 * i;
    const int kb = t * 64;
    const bool s2 = (t + 2 < KT), s3 = (t + 3 < KT);

    // ph1: q(m0,n0) tile t. reads A0(8)+B0(4). stage Ah0(t+1)->buf1.
    READ_A(b0, 0)
    READ_B(b0, 0, bR0)
    STG_A(1, 0, kb + 64);
    LGKM(8);
    PH_MID();
    MFMA_Q(0, 0, bR0)
    PH_CUT();

    // ph2: q(m0,n1). reads B1(4). stage Ah1(t+1)->buf1.
    READ_B(b0, 1, bR1)
    STG_A(1, 1, kb + 64);
    PH_MID();
    MFMA_Q(0, 1, bR1)
    PH_CUT();

    // ph3: q(m1,n1). reads A1(8). stage Bh0(t+2)->buf0
    // (safe: passing ph2-MID implies all waves' ph1 B0 reads completed).
    READ_A(b0, 1)
    if (s2) STG_B(0, 0, kb + 128);
    PH_MID();
    MFMA_Q(1, 1, bR1)
    PH_CUT();

    // ph4: q(m1,n0). no reads. stage Bh1(t+2)->buf0.
    if (s2) STG_B(0, 1, kb + 128);
    PH_MID();
    MFMA_Q(1, 0, bR0)
    PH_CUT();
    if (s2) { VMC(4); } else { VMC(0); }  // t+1's 8 loads landed
    BAR();

    // ph5: q(m0,n0) tile t+1 from buf1. stage Ah0(t+2)->buf0.
    READ_A(b1, 0)
    READ_B(b1, 0, bR0)
    if (s2) STG_A(0, 0, kb + 128);
    LGKM(8);
    PH_MID();
    MFMA_Q(0, 0, bR0)
    PH_CUT();

    // ph6: q(m0,n1). reads B1. stage Ah1(t+2)->buf0.
    READ_B(b1, 1, bR1)
    if (s2) STG_A(0, 1, kb + 128);
    PH_MID();
    MFMA_Q(0, 1, bR1)
    PH_CUT();

    // ph7: q(m1,n1). reads A1. stage Bh0(t+3)->buf1.
    READ_A(b1, 1)
    if (s3) STG_B(1, 0, kb + 192);
    PH_MID();
    MFMA_Q(1, 1, bR1)
    PH_CUT();

    // ph8: q(m1,n0). no reads. stage Bh1(t+3)->buf1.
    if (s3) STG_B(1, 1, kb + 192);
    PH_MID();
    MFMA_Q(1, 0, bR0)
    PH_CUT();
    if (s3) { VMC(4); } else { VMC(0); }
    BAR();
  }

  // epilogue: 16x16 C/D layout (m89-verified): col=lane&15, row=(lane>>4)*4+j
#pragma unroll
  for (int mf = 0; mf < 8; ++mf) {
#pragma unroll
    for (int nf = 0; nf < 4; ++nf) {
      const int gr = row0 + wr * 128 + mf * 16 + (lane >> 4) * 4;
      const int gc = col0 + wc * 64 + nf * 16 + l15;
      float* cp = C + (size_t)gr * N_DIM + gc;
#pragma unroll
      for (int j = 0; j < 4; ++j) cp[(size_t)j * N_DIM] = acc[mf][nf][j];
    }
  }
}

// ---- fallback (ws too small): reg-staged f32->bf16 kernel ------------------
__global__ __launch_bounds__(256) void gemm_fb(const float* __restrict__ Af,
                                               const float* __restrict__ Bf,
                                               float* __restrict__ C) {
  __shared__ unsigned short sA[128 * 64];
  __shared__ unsigned short sB[128 * 64];
  const int tid = threadIdx.x;
  const int lane = tid & 63;
  const int wid = tid >> 6;
  const int wr = wid >> 1, wc = wid & 1;
  const int cpx = (int)gridDim.x >> 3;
  const int swzb = ((int)blockIdx.x & 7) * cpx + ((int)blockIdx.x >> 3);
  const int row0 = (swzb / (N_DIM / 128)) * 128;
  const int col0 = (swzb % (N_DIM / 128)) * 128;
  f32x4 acc[4][4] = {};
  const int fbase = tid * 8;
  for (int kt = 0; kt < K_DIM; kt += 64) {
#pragma unroll
    for (int p = 0; p < 4; ++p) {
      const int f = fbase + p * 2048;
      const int r = f >> 6, kc = f & 63;
      const float* gA = Af + (size_t)(row0 + r) * K_DIM + kt + kc;
      const float* gB = Bf + (size_t)(col0 + r) * K_DIM + kt + kc;
      f32x4 a0 = ((const f32x4*)gA)[0], a1 = ((const f32x4*)gA)[1];
      f32x4 c0 = ((const f32x4*)gB)[0], c1 = ((const f32x4*)gB)[1];
      u16x8 va, vb;
      va[0] = f2bf(a0[0]); va[1] = f2bf(a0[1]); va[2] = f2bf(a0[2]); va[3] = f2bf(a0[3]);
      va[4] = f2bf(a1[0]); va[5] = f2bf(a1[1]); va[6] = f2bf(a1[2]); va[7] = f2bf(a1[3]);
      vb[0] = f2bf(c0[0]); vb[1] = f2bf(c0[1]); vb[2] = f2bf(c0[2]); vb[3] = f2bf(c0[3]);
      vb[4] = f2bf(c1[0]); vb[5] = f2bf(c1[1]); vb[6] = f2bf(c1[2]); vb[7] = f2bf(c1[3]);
      *(u16x8*)&sA[f] = va;
      *(u16x8*)&sB[f] = vb;
    }
    __syncthreads();
#pragma unroll
    for (int kk = 0; kk < 2; ++kk) {
      bf16x8 a[4], b[4];
#pragma unroll
      for (int m = 0; m < 4; ++m)
        a[m] = *(const bf16x8*)&sA[(wr * 64 + m * 16 + (lane & 15)) * 64 + kk * 32 + (lane >> 4) * 8];
#pragma unroll
      for (int n = 0; n < 4; ++n)
        b[n] = *(const bf16x8*)&sB[(wc * 64 + n * 16 + (lane & 15)) * 64 + kk * 32 + (lane >> 4) * 8];
#pragma unroll
      for (int m = 0; m < 4; ++m)
#pragma unroll
        for (int n = 0; n < 4; ++n)
          acc[m][n] = __builtin_amdgcn_mfma_f32_16x16x32_bf16(a[m], b[n], acc[m][n], 0, 0, 0);
    }
    __syncthreads();
  }
#pragma unroll
  for (int m = 0; m < 4; ++m)
#pragma unroll
    for (int n = 0; n < 4; ++n) {
      const int gr = row0 + wr * 64 + m * 16 + (lane >> 4) * 4;
      const int gc = col0 + wc * 64 + n * 16 + (lane & 15);
      float* cp = C + (size_t)gr * N_DIM + gc;
#pragma unroll
      for (int j = 0; j < 4; ++j) cp[(size_t)j * N_DIM] = acc[m][n][j];
    }
}

extern "C" void kernel_launch(void* const* d_in, const int* in_sizes, int n_in,
                              void* d_out, int out_size, void* d_ws, size_t ws_size,
                              hipStream_t stream) {
  const float* x = (const float*)d_in[0];  // [8192, 4096]
  const float* W = (const float*)d_in[1];  // [4096, 4096]
  float* out = (float*)d_out;              // [8192, 4096] f32

  const size_t xb_bytes = (size_t)M_DIM * K_DIM * 2;  // 64 MiB
  const size_t wb_bytes = (size_t)N_DIM * K_DIM * 2;  // 32 MiB

  if (ws_size >= xb_bytes + wb_bytes) {
    unsigned short* Xb = (unsigned short*)d_ws;
    unsigned short* Wb = (unsigned short*)((char*)d_ws + xb_bytes);
    cvt_fused<<<2048, 256, 0, stream>>>(x, Xb, (long)M_DIM * K_DIM / 8,
                                        W, Wb, (long)N_DIM * K_DIM / 8);
    const dim3 grid((M_DIM / BM) * (N_DIM / BN));  // 32*16 = 512 blocks
    gemmR10<<<grid, dim3(512), 0, stream>>>(Xb, Wb, out);
  } else {
    gemm_fb<<<dim3(2048), dim3(256), 0, stream>>>(x, W, out);
  }
}

// Round 15
// 253.933 us; speedup vs baseline: 1.1899x; 1.0009x over previous
//
#include <hip/hip_runtime.h>
#include <hip/hip_bf16.h>

// SparseLinear as dense bf16 MFMA GEMM: out[b,o] = sum_i x[b,i]*W[o,i]
// C = A * B^T, M=8192, N=4096, K=4096. bias is dead in the reference.
// FINAL (R15 == R14, the measured session optimum: total 254us,
// GEMM 228us / ~1140 TF, MfmaUtil 52.9%, 0 bank conflicts, absmax 0.5).
// Structure: fused f32->bf16 convert into ws, then 256x256-tile GEMM,
// BK=64, 8 waves (2Mx4N), 16x16x32 MFMA, LDS 128 KiB = buf[2] x
// {A[256][64k], B[256][64k]}; quadrant phases {12,4,8,0} ds_read_b128
// issued PRE-barrier / consumed POST-barrier, single MID barrier per
// phase (waves de-phase <=1 phase -> cross-wave LDS/MFMA overlap),
// 1 half-tile staged per phase, minimal-wait vmcnt(4) gate per K-tile.
// T1 XCD swizzle; T2 XOR swizzle byte^=((row&7)<<4), loop-invariant
// k-half XOR bases precomputed; staging sources inverse-swizzled.
// Session ledger: counted-LGKM read-ahead (pre- and post-barrier),
// 32x32x16 shape, 2-blk/CU co-residency, free-run 1-bar/tile, and
// coarse phases all measured worse. This kernel is the family optimum.

typedef short bf16x8 __attribute__((ext_vector_type(8)));
typedef float f32x4 __attribute__((ext_vector_type(4)));
typedef unsigned short u16x8 __attribute__((ext_vector_type(8)));

static constexpr int M_DIM = 8192;
static constexpr int N_DIM = 4096;
static constexpr int K_DIM = 4096;
static constexpr int BM = 256, BN = 256, BK = 64;
static constexpr int KT = K_DIM / BK;  // 64 K-tiles, 32 iters x 2 tiles

__device__ __forceinline__ unsigned short f2bf(float f) {
  unsigned int u = __builtin_bit_cast(unsigned int, f);
  u += 0x7fffu + ((u >> 16) & 1u);
  return (unsigned short)(u >> 16);
}

// fused convert: grid-stride over x (nx8 vec8 chunks) then W (nw8 chunks)
__global__ void cvt_fused(const float* __restrict__ x,
                          unsigned short* __restrict__ xo, long nx8,
                          const float* __restrict__ w,
                          unsigned short* __restrict__ wo, long nw8) {
  const long stride = (long)gridDim.x * blockDim.x;
  long i = (long)blockIdx.x * blockDim.x + threadIdx.x;
  for (; i < nx8 + nw8; i += stride) {
    const float* in = (i < nx8) ? x : w;
    unsigned short* out = (i < nx8) ? xo : wo;
    const long j = (i < nx8) ? i : i - nx8;
    f32x4 a = ((const f32x4*)in)[2 * j];
    f32x4 b = ((const f32x4*)in)[2 * j + 1];
    u16x8 v;
    v[0] = f2bf(a[0]); v[1] = f2bf(a[1]); v[2] = f2bf(a[2]); v[3] = f2bf(a[3]);
    v[4] = f2bf(b[0]); v[5] = f2bf(b[1]); v[6] = f2bf(b[2]); v[7] = f2bf(b[3]);
    ((u16x8*)out)[j] = v;
  }
}

#define LGKM(N) asm volatile("s_waitcnt lgkmcnt(" #N ")" ::: "memory")
#define VMC(N) asm volatile("s_waitcnt vmcnt(" #N ")" ::: "memory")
#define SB0() __builtin_amdgcn_sched_barrier(0)
#define BAR()                        \
  do {                               \
    asm volatile("" ::: "memory");   \
    __builtin_amdgcn_s_barrier();    \
    asm volatile("" ::: "memory");   \
  } while (0)

__device__ __forceinline__ void gload16(const unsigned short* src,
                                        unsigned short* dst) {
  __builtin_amdgcn_global_load_lds(
      (const __attribute__((address_space(1))) void*)src,
      (__attribute__((address_space(3))) void*)dst, 16, 0, 0);
}

// Per-buffer layout (bytes): A rows 0-255 @0 (32 KB), B rows 0-255 @32768.
// Row stride 128 B. Swizzle: byte ^= ((row&7)<<4); row&7 == lane&7 for all
// fragment reads. k-half offset (64 = bit 6) XOR-composes; loop-invariant,
// so both bases precomputed. mh/nh/fr offsets (>=2^11) add without carry.

__global__ __launch_bounds__(512, 2) void gemmR10(
    const unsigned short* __restrict__ Ab, const unsigned short* __restrict__ Bb,
    float* __restrict__ C) {
  __shared__ unsigned short lds[2][32768];  // 2 x 64 KB

  const int tid = threadIdx.x;
  const int lane = tid & 63;
  const int wid = tid >> 6;   // 8 waves: 2M x 4N, wave-tile 128 x 64
  const int wr = wid >> 2;    // 0..1
  const int wc = wid & 3;     // 0..3
  const int l15 = lane & 15;

  // T1: XCD-aware bijective swizzle (512 blocks, %8==0)
  const int b0i = blockIdx.x;
  const int swz = (b0i & 7) * ((int)gridDim.x >> 3) + (b0i >> 3);
  const int row0 = (swz / (N_DIM / BN)) * BM;
  const int col0 = (swz % (N_DIM / BN)) * BN;

  // swizzled read bases (bytes, buffer-relative); k-half XOR precomputed
  const int kg = (((lane >> 4) << 4) ^ ((lane & 7) << 4));
  const int abase = wr * 16384 + l15 * 128 + kg;
  const int abase2 = abase ^ 64;
  const int bbase = 32768 + (wc >> 1) * 16384 + (wc & 1) * 8192 + l15 * 128 + kg;
  const int bbase2 = bbase ^ 64;

  // staging: inverse-swizzled global sources [half][inst]
  const unsigned short* pA[2][2];
  const unsigned short* pB[2][2];
#pragma unroll
  for (int r = 0; r < 2; ++r) {
    int q = r * 8192 + tid * 16;
    int lo = q ^ (((q >> 7) & 7) << 4);
    int grow = lo >> 7;            // 0..127
    int gk = (lo & 127) >> 1;      // 0..63
#pragma unroll
    for (int h = 0; h < 2; ++h) {
      pA[h][r] = Ab + (size_t)(row0 + h * 128 + grow) * K_DIM + gk;
      pB[h][r] = Bb + (size_t)(col0 + h * 128 + grow) * K_DIM + gk;
    }
  }

#define STG_A(BUF, H, KEL)                                                 \
  do {                                                                     \
    gload16(pA[H][0] + (KEL), &lds[BUF][0] + (H) * 8192 + wid * 512);      \
    gload16(pA[H][1] + (KEL), &lds[BUF][0] + (H) * 8192 + 4096 + wid * 512); \
  } while (0)
#define STG_B(BUF, H, KEL)                                                 \
  do {                                                                     \
    gload16(pB[H][0] + (KEL), &lds[BUF][0] + 16384 + (H) * 8192 + wid * 512); \
    gload16(pB[H][1] + (KEL), &lds[BUF][0] + 16384 + (H) * 8192 + 4096 + wid * 512); \
  } while (0)

  f32x4 acc[8][4] = {};
  bf16x8 aR[8], bR0[4], bR1[4];

#define READ_A(BUF, MH)                                                    \
  _Pragma("unroll") for (int fr = 0; fr < 4; ++fr) {                       \
    aR[fr * 2 + 0] = *(const bf16x8*)((BUF) + abase + (MH) * 8192 + fr * 2048);  \
    aR[fr * 2 + 1] = *(const bf16x8*)((BUF) + abase2 + (MH) * 8192 + fr * 2048); \
  }
#define READ_B(BUF, NH, BR)                                                \
  _Pragma("unroll") for (int nf = 0; nf < 2; ++nf) {                       \
    BR[nf * 2 + 0] = *(const bf16x8*)((BUF) + bbase + (NH) * 4096 + nf * 2048);  \
    BR[nf * 2 + 1] = *(const bf16x8*)((BUF) + bbase2 + (NH) * 4096 + nf * 2048); \
  }
#define MFMA_Q(MH, NH, BR)                                                 \
  _Pragma("unroll") for (int fr = 0; fr < 4; ++fr)                         \
    _Pragma("unroll") for (int nf = 0; nf < 2; ++nf) {                     \
      acc[(MH) * 4 + fr][(NH) * 2 + nf] =                                  \
          __builtin_amdgcn_mfma_f32_16x16x32_bf16(                         \
              aR[fr * 2 + 0], BR[nf * 2 + 0],                              \
              acc[(MH) * 4 + fr][(NH) * 2 + nf], 0, 0, 0);                 \
      acc[(MH) * 4 + fr][(NH) * 2 + nf] =                                  \
          __builtin_amdgcn_mfma_f32_16x16x32_bf16(                         \
              aR[fr * 2 + 1], BR[nf * 2 + 1],                              \
              acc[(MH) * 4 + fr][(NH) * 2 + nf], 0, 0, 0);                 \
    }
// Single load-bearing barrier per phase (MID). Stage deadlines are
// guaranteed by the MID barrier chain (R10 ledger).
#define PH_MID()  BAR(); LGKM(0); SB0(); __builtin_amdgcn_s_setprio(1)
#define PH_CUT()  __builtin_amdgcn_s_setprio(0)

  // prologue: tile0 (4 halves -> buf0) + tile1's B halves -> buf1.
  STG_A(0, 0, 0); STG_A(0, 1, 0); STG_B(0, 0, 0); STG_B(0, 1, 0);
  STG_B(1, 0, 64); STG_B(1, 1, 64);
  VMC(4);
  BAR();

  const char* b0 = (const char*)&lds[0][0];
  const char* b1 = (const char*)&lds[1][0];

#pragma unroll 1
  for (int i = 0; i < KT / 2; ++i) {
    const int t = 2 * i;
    const int kb = t * 64;
    const bool s2 = (t + 2 < KT), s3 = (t + 3 < KT);

    // ph1: q(m0,n0) tile t. reads A0(8)+B0(4). stage Ah0(t+1)->buf1.
    READ_A(b0, 0)
    READ_B(b0, 0, bR0)
    STG_A(1, 0, kb + 64);
    LGKM(8);
    PH_MID();
    MFMA_Q(0, 0, bR0)
    PH_CUT();

    // ph2: q(m0,n1). reads B1(4). stage Ah1(t+1)->buf1.
    READ_B(b0, 1, bR1)
    STG_A(1, 1, kb + 64);
    PH_MID();
    MFMA_Q(0, 1, bR1)
    PH_CUT();

    // ph3: q(m1,n1). reads A1(8). stage Bh0(t+2)->buf0
    // (safe: passing ph2-MID implies all waves' ph1 B0 reads completed).
    READ_A(b0, 1)
    if (s2) STG_B(0, 0, kb + 128);
    PH_MID();
    MFMA_Q(1, 1, bR1)
    PH_CUT();

    // ph4: q(m1,n0). no reads. stage Bh1(t+2)->buf0.
    if (s2) STG_B(0, 1, kb + 128);
    PH_MID();
    MFMA_Q(1, 0, bR0)
    PH_CUT();
    if (s2) { VMC(4); } else { VMC(0); }  // t+1's 8 loads landed
    BAR();

    // ph5: q(m0,n0) tile t+1 from buf1. stage Ah0(t+2)->buf0.
    READ_A(b1, 0)
    READ_B(b1, 0, bR0)
    if (s2) STG_A(0, 0, kb + 128);
    LGKM(8);
    PH_MID();
    MFMA_Q(0, 0, bR0)
    PH_CUT();

    // ph6: q(m0,n1). reads B1. stage Ah1(t+2)->buf0.
    READ_B(b1, 1, bR1)
    if (s2) STG_A(0, 1, kb + 128);
    PH_MID();
    MFMA_Q(0, 1, bR1)
    PH_CUT();

    // ph7: q(m1,n1). reads A1. stage Bh0(t+3)->buf1.
    READ_A(b1, 1)
    if (s3) STG_B(1, 0, kb + 192);
    PH_MID();
    MFMA_Q(1, 1, bR1)
    PH_CUT();

    // ph8: q(m1,n0). no reads. stage Bh1(t+3)->buf1.
    if (s3) STG_B(1, 1, kb + 192);
    PH_MID();
    MFMA_Q(1, 0, bR0)
    PH_CUT();
    if (s3) { VMC(4); } else { VMC(0); }
    BAR();
  }

  // epilogue: 16x16 C/D layout (m89-verified): col=lane&15, row=(lane>>4)*4+j
#pragma unroll
  for (int mf = 0; mf < 8; ++mf) {
#pragma unroll
    for (int nf = 0; nf < 4; ++nf) {
      const int gr = row0 + wr * 128 + mf * 16 + (lane >> 4) * 4;
      const int gc = col0 + wc * 64 + nf * 16 + l15;
      float* cp = C + (size_t)gr * N_DIM + gc;
#pragma unroll
      for (int j = 0; j < 4; ++j) cp[(size_t)j * N_DIM] = acc[mf][nf][j];
    }
  }
}

// ---- fallback (ws too small): reg-staged f32->bf16 kernel ------------------
__global__ __launch_bounds__(256) void gemm_fb(const float* __restrict__ Af,
                                               const float* __restrict__ Bf,
                                               float* __restrict__ C) {
  __shared__ unsigned short sA[128 * 64];
  __shared__ unsigned short sB[128 * 64];
  const int tid = threadIdx.x;
  const int lane = tid & 63;
  const int wid = tid >> 6;
  const int wr = wid >> 1, wc = wid & 1;
  const int cpx = (int)gridDim.x >> 3;
  const int swzb = ((int)blockIdx.x & 7) * cpx + ((int)blockIdx.x >> 3);
  const int row0 = (swzb / (N_DIM / 128)) * 128;
  const int col0 = (swzb % (N_DIM / 128)) * 128;
  f32x4 acc[4][4] = {};
  const int fbase = tid * 8;
  for (int kt = 0; kt < K_DIM; kt += 64) {
#pragma unroll
    for (int p = 0; p < 4; ++p) {
      const int f = fbase + p * 2048;
      const int r = f >> 6, kc = f & 63;
      const float* gA = Af + (size_t)(row0 + r) * K_DIM + kt + kc;
      const float* gB = Bf + (size_t)(col0 + r) * K_DIM + kt + kc;
      f32x4 a0 = ((const f32x4*)gA)[0], a1 = ((const f32x4*)gA)[1];
      f32x4 c0 = ((const f32x4*)gB)[0], c1 = ((const f32x4*)gB)[1];
      u16x8 va, vb;
      va[0] = f2bf(a0[0]); va[1] = f2bf(a0[1]); va[2] = f2bf(a0[2]); va[3] = f2bf(a0[3]);
      va[4] = f2bf(a1[0]); va[5] = f2bf(a1[1]); va[6] = f2bf(a1[2]); va[7] = f2bf(a1[3]);
      vb[0] = f2bf(c0[0]); vb[1] = f2bf(c0[1]); vb[2] = f2bf(c0[2]); vb[3] = f2bf(c0[3]);
      vb[4] = f2bf(c1[0]); vb[5] = f2bf(c1[1]); vb[6] = f2bf(c1[2]); vb[7] = f2bf(c1[3]);
      *(u16x8*)&sA[f] = va;
      *(u16x8*)&sB[f] = vb;
    }
    __syncthreads();
#pragma unroll
    for (int kk = 0; kk < 2; ++kk) {
      bf16x8 a[4], b[4];
#pragma unroll
      for (int m = 0; m < 4; ++m)
        a[m] = *(const bf16x8*)&sA[(wr * 64 + m * 16 + (lane & 15)) * 64 + kk * 32 + (lane >> 4) * 8];
#pragma unroll
      for (int n = 0; n < 4; ++n)
        b[n] = *(const bf16x8*)&sB[(wc * 64 + n * 16 + (lane & 15)) * 64 + kk * 32 + (lane >> 4) * 8];
#pragma unroll
      for (int m = 0; m < 4; ++m)
#pragma unroll
        for (int n = 0; n < 4; ++n)
          acc[m][n] = __builtin_amdgcn_mfma_f32_16x16x32_bf16(a[m], b[n], acc[m][n], 0, 0, 0);
    }
    __syncthreads();
  }
#pragma unroll
  for (int m = 0; m < 4; ++m)
#pragma unroll
    for (int n = 0; n < 4; ++n) {
      const int gr = row0 + wr * 64 + m * 16 + (lane >> 4) * 4;
      const int gc = col0 + wc * 64 + n * 16 + (lane & 15);
      float* cp = C + (size_t)gr * N_DIM + gc;
#pragma unroll
      for (int j = 0; j < 4; ++j) cp[(size_t)j * N_DIM] = acc[m][n][j];
    }
}

extern "C" void kernel_launch(void* const* d_in, const int* in_sizes, int n_in,
                              void* d_out, int out_size, void* d_ws, size_t ws_size,
                              hipStream_t stream) {
  const float* x = (const float*)d_in[0];  // [8192, 4096]
  const float* W = (const float*)d_in[1];  // [4096, 4096]
  float* out = (float*)d_out;              // [8192, 4096] f32

  const size_t xb_bytes = (size_t)M_DIM * K_DIM * 2;  // 64 MiB
  const size_t wb_bytes = (size_t)N_DIM * K_DIM * 2;  // 32 MiB

  if (ws_size >= xb_bytes + wb_bytes) {
    unsigned short* Xb = (unsigned short*)d_ws;
    unsigned short* Wb = (unsigned short*)((char*)d_ws + xb_bytes);
    cvt_fused<<<2048, 256, 0, stream>>>(x, Xb, (long)M_DIM * K_DIM / 8,
                                        W, Wb, (long)N_DIM * K_DIM / 8);
    const dim3 grid((M_DIM / BM) * (N_DIM / BN));  // 32*16 = 512 blocks
    gemmR10<<<grid, dim3(512), 0, stream>>>(Xb, Wb, out);
  } else {
    gemm_fb<<<dim3(2048), dim3(256), 0, stream>>>(x, W, out);
  }
}